// Round 3
// baseline (578.326 us; speedup 1.0000x reference)
//
#include <hip/hip_runtime.h>

#define NK 512
#define ND 64
#define NHW 4096
#define NPIX 131072            // 32*64*64
#define OUT_ELEMS 8388608      // 32*64*64*64

// ---------------------------------------------------------------------------
// Prep: sc[k] = numpy-pairwise-8 fp32 sum of fl(c_d^2)  (emulates
// np.sum(cb*cb, axis=1)); also zero the two loss slots in d_out (harness
// re-poisons d_out/d_ws to 0xAA before every timed replay).
// ---------------------------------------------------------------------------
__global__ __launch_bounds__(256) void vq_prep(const float* __restrict__ cb,
                                               float* __restrict__ sc,
                                               float* __restrict__ losses) {
#pragma clang fp contract(off)
  {
    int k = blockIdx.x * 256 + threadIdx.x;   // grid 2*256 = 512
    const float* c = cb + (size_t)k * ND;
    float q[ND];
#pragma unroll
    for (int d = 0; d < ND; ++d) q[d] = c[d] * c[d];
    float r[8];
#pragma unroll
    for (int j = 0; j < 8; ++j) r[j] = q[j];
#pragma unroll
    for (int i = 8; i < ND; i += 8)
#pragma unroll
      for (int j = 0; j < 8; ++j) r[j] += q[i + j];
    float res = ((r[0] + r[1]) + (r[2] + r[3])) + ((r[4] + r[5]) + (r[6] + r[7]));
    sc[k] = res;
    if (k < 2) losses[k] = 0.f;
  }
}

// ---------------------------------------------------------------------------
// Main: 2 threads per pixel (K sliced 256+256). Numerics bitwise-identical to
// the passing round-2 kernel: d2[k] = fl(fl(Sx - fl(2*M[k])) + Sc[k]) with
// M[k] a sequential fp32 FMA chain, Sx numpy-pairwise-8. Merge across slices
// with strict '<' so the lowest index wins ties (= np.argmin over full K).
//
// __launch_bounds__(256, 4): 4 waves/EU target -> VGPR cap 128, so xr[64]
// stays register-resident (round-2's bare bound made the compiler target 64
// VGPRs and spill xr). Grid 1024 blocks = 4 blocks/CU = 16 waves/CU.
// ---------------------------------------------------------------------------
__global__ __launch_bounds__(256, 4) void vq_main(const float* __restrict__ x,
                                                  const float* __restrict__ cb,
                                                  const float* __restrict__ sc,
                                                  float* __restrict__ out,
                                                  float* __restrict__ idx_out,
                                                  float* __restrict__ losses) {
#pragma clang fp contract(off)
  {
    const int tid = threadIdx.x;
    const int pixl = tid & 127;         // pixel within block
    const int slice = tid >> 7;         // 0: k<256, 1: k>=256
    const int g = blockIdx.x * 128 + pixl;
    const int b = g >> 12;
    const int hw = g & 4095;
    const float* xp = x + (size_t)b * (ND * NHW) + hw;

    float xr[ND];
#pragma unroll
    for (int d = 0; d < ND; ++d) xr[d] = xp[(size_t)d * NHW];  // coalesced

    // Sx = np.sum(x*x): rounded squares, pairwise-8 (same bits in both slices)
    float r[8];
#pragma unroll
    for (int j = 0; j < 8; ++j) r[j] = xr[j] * xr[j];
#pragma unroll
    for (int i = 8; i < ND; i += 8)
#pragma unroll
      for (int j = 0; j < 8; ++j) r[j] += xr[i + j] * xr[i + j];
    const float Sx = ((r[0] + r[1]) + (r[2] + r[3])) + ((r[4] + r[5]) + (r[6] + r[7]));

    float m1 = 3.0e38f;
    const int k0 = slice << 8;
    int i1 = k0;

    for (int kk = 0; kk < NK / 2; kk += 4) {   // 4 sequential chains for ILP
      const int k = k0 + kk;
      const float* c0 = cb + (size_t)(k + 0) * ND;   // wave-uniform -> s_load
      const float* c1 = cb + (size_t)(k + 1) * ND;
      const float* c2 = cb + (size_t)(k + 2) * ND;
      const float* c3 = cb + (size_t)(k + 3) * ND;
      float a0 = 0.f, a1 = 0.f, a2 = 0.f, a3 = 0.f;
#pragma unroll
      for (int d = 0; d < ND; ++d) {            // sequential FMA chain = BLAS
        a0 = __builtin_fmaf(c0[d], xr[d], a0);
        a1 = __builtin_fmaf(c1[d], xr[d], a1);
        a2 = __builtin_fmaf(c2[d], xr[d], a2);
        a3 = __builtin_fmaf(c3[d], xr[d], a3);
      }
      float d20 = (Sx - 2.0f * a0) + sc[k + 0];
      float d21 = (Sx - 2.0f * a1) + sc[k + 1];
      float d22 = (Sx - 2.0f * a2) + sc[k + 2];
      float d23 = (Sx - 2.0f * a3) + sc[k + 3];
      if (d20 < m1) { m1 = d20; i1 = k + 0; }   // in-order: lowest index wins
      if (d21 < m1) { m1 = d21; i1 = k + 1; }
      if (d22 < m1) { m1 = d22; i1 = k + 2; }
      if (d23 < m1) { m1 = d23; i1 = k + 3; }
    }

    // Merge slices: slice 1 wins only on strict '<' (lower k wins ties).
    __shared__ float sh_m[128];
    __shared__ int sh_i[128];
    __shared__ int sh_w[128];
    if (slice == 1) { sh_m[pixl] = m1; sh_i[pixl] = i1; }
    __syncthreads();
    if (slice == 0) {
      if (sh_m[pixl] < m1) { m1 = sh_m[pixl]; i1 = sh_i[pixl]; }
      sh_w[pixl] = i1;
      idx_out[g] = (float)i1;                   // coalesced (threads 0..127)
    }
    __syncthreads();
    const int widx = sh_w[pixl];

    // Epilogue split: each slice-thread gathers/writes 32 of the 64 dims and
    // accumulates its loss partial. Codebook row is L2-resident.
    const float4* q4 = (const float4*)(cb + (size_t)widx * ND) + slice * 8;
    float* op = out + (size_t)b * (ND * NHW) + hw;
    const int dbase = slice * 32;
    float lossp = 0.f;
#pragma unroll
    for (int j = 0; j < 8; ++j) {
      float4 q = q4[j];
      int d = dbase + j * 4;
      float e;
      e = xr[d + 0] - q.x; lossp = __builtin_fmaf(e, e, lossp); op[(size_t)(d + 0) * NHW] = q.x;
      e = xr[d + 1] - q.y; lossp = __builtin_fmaf(e, e, lossp); op[(size_t)(d + 1) * NHW] = q.y;
      e = xr[d + 2] - q.z; lossp = __builtin_fmaf(e, e, lossp); op[(size_t)(d + 2) * NHW] = q.z;
      e = xr[d + 3] - q.w; lossp = __builtin_fmaf(e, e, lossp); op[(size_t)(d + 3) * NHW] = q.w;
    }

    // Loss reduction: wave shuffle, then cross-wave via LDS, one atomic pair
    // per block (1024 blocks).
#pragma unroll
    for (int off = 32; off; off >>= 1) lossp += __shfl_down(lossp, off);
    __shared__ float red[4];
    const int lane = tid & 63, wid = tid >> 6;
    if (lane == 0) red[wid] = lossp;
    __syncthreads();
    if (tid == 0) {
      float t = (red[0] + red[1] + red[2] + red[3]) * (1.f / 8388608.f);
      atomicAdd(losses + 0, t);   // dictionary_loss
      atomicAdd(losses + 1, t);   // commitment_loss (identical forward value)
    }
  }
}

extern "C" void kernel_launch(void* const* d_in, const int* in_sizes, int n_in,
                              void* d_out, int out_size, void* d_ws, size_t ws_size,
                              hipStream_t stream) {
  const float* x  = (const float*)d_in[0];   // [32,64,64,64] fp32
  const float* cb = (const float*)d_in[1];   // [512,64] fp32
  float* out     = (float*)d_out;            // quantized [B,D,H,W]
  float* idx_out = out + OUT_ELEMS;          // indices (as fp32) [B,H,W]
  float* losses  = idx_out + NPIX;           // 2 scalars
  float* sc      = (float*)d_ws;             // 512 floats scratch

  vq_prep<<<2, 256, 0, stream>>>(cb, sc, losses);
  vq_main<<<NPIX / 128, 256, 0, stream>>>(x, cb, sc, out, idx_out, losses);
}

// Round 4
// 260.487 us; speedup vs baseline: 2.2202x; 2.2202x over previous
//
#include <hip/hip_runtime.h>

#define NK 512
#define ND 64
#define NHW 4096
#define NPIX 131072            // 32*64*64
#define OUT_ELEMS 8388608      // 32*64*64*64

// ---------------------------------------------------------------------------
// Prep: sc[k] = numpy-pairwise-8 fp32 sum of fl(c_d^2); zero the two loss
// slots (harness re-poisons d_out/d_ws to 0xAA before every timed replay).
// ---------------------------------------------------------------------------
__global__ __launch_bounds__(256) void vq_prep(const float* __restrict__ cb,
                                               float* __restrict__ sc,
                                               float* __restrict__ losses) {
#pragma clang fp contract(off)
  {
    int k = blockIdx.x * 256 + threadIdx.x;   // grid 2*256 = 512
    const float* c = cb + (size_t)k * ND;
    float q[ND];
#pragma unroll
    for (int d = 0; d < ND; ++d) q[d] = c[d] * c[d];
    float r[8];
#pragma unroll
    for (int j = 0; j < 8; ++j) r[j] = q[j];
#pragma unroll
    for (int i = 8; i < ND; i += 8)
#pragma unroll
      for (int j = 0; j < 8; ++j) r[j] += q[i + j];
    float res = ((r[0] + r[1]) + (r[2] + r[3])) + ((r[4] + r[5]) + (r[6] + r[7]));
    sc[k] = res;
    if (k < 2) losses[k] = 0.f;
  }
}

// ---------------------------------------------------------------------------
// Main: 64 pixels/block, 4 waves = 4 K-slices of 128 codes each.
// slice goes through readfirstlane -> SGPR -> codebook addresses provably
// wave-uniform -> s_load streaming (round 2's fast path), while occupancy is
// 4x round 2 (8192 waves). amdgpu_waves_per_eu(4,6) stops the allocator from
// squeezing below ~xr[64]+acc (rounds 2/3 spilled/remat at 44/56 VGPRs).
// Numerics bit-identical to the passing round-2 kernel:
//   d2[k] = fl(fl(Sx - fl(2*M[k])) + Sc[k]), M[k] sequential fp32 FMA chain,
//   Sx numpy pairwise-8. In-block merge in slice order with strict '<'
//   => lowest index wins ties = np.argmin over full K.
// ---------------------------------------------------------------------------
__global__ __launch_bounds__(256)
__attribute__((amdgpu_waves_per_eu(4, 6)))
void vq_main(const float* __restrict__ x,
             const float* __restrict__ cb,
             const float* __restrict__ sc,
             float* __restrict__ out,
             float* __restrict__ idx_out,
             float* __restrict__ losses) {
#pragma clang fp contract(off)
  {
    const int tid = threadIdx.x;
    const int p = tid & 63;                                   // pixel lane
    const int wave = __builtin_amdgcn_readfirstlane(tid >> 6); // 0..3, SGPR
    const int g = blockIdx.x * 64 + p;
    const int b = g >> 12;
    const int hw = g & 4095;
    const float* xp = x + (size_t)b * (ND * NHW) + hw;

    float xr[ND];
#pragma unroll
    for (int d = 0; d < ND; ++d) xr[d] = xp[(size_t)d * NHW];  // coalesced

    // Sx = np.sum(x*x): rounded squares, pairwise-8 (same bits every slice).
    float r[8];
#pragma unroll
    for (int j = 0; j < 8; ++j) r[j] = xr[j] * xr[j];
#pragma unroll
    for (int i = 8; i < ND; i += 8)
#pragma unroll
      for (int j = 0; j < 8; ++j) r[j] += xr[i + j] * xr[i + j];
    const float Sx = ((r[0] + r[1]) + (r[2] + r[3])) + ((r[4] + r[5]) + (r[6] + r[7]));

    // This wave's K-slice: [wave*128, wave*128+128). k0 is SGPR-resident.
    const int k0 = wave << 7;
    float m1 = 3.0e38f;
    int i1 = k0;

    for (int kk = 0; kk < 128; kk += 4) {       // 4 sequential chains for ILP
      const int k = k0 + kk;                    // uniform -> s_load rows
      const float* c0 = cb + (size_t)(k + 0) * ND;
      const float* c1 = cb + (size_t)(k + 1) * ND;
      const float* c2 = cb + (size_t)(k + 2) * ND;
      const float* c3 = cb + (size_t)(k + 3) * ND;
      float a0 = 0.f, a1 = 0.f, a2 = 0.f, a3 = 0.f;
#pragma unroll
      for (int d = 0; d < ND; ++d) {            // sequential FMA chain = BLAS
        a0 = __builtin_fmaf(c0[d], xr[d], a0);
        a1 = __builtin_fmaf(c1[d], xr[d], a1);
        a2 = __builtin_fmaf(c2[d], xr[d], a2);
        a3 = __builtin_fmaf(c3[d], xr[d], a3);
      }
      float d20 = (Sx - 2.0f * a0) + sc[k + 0];
      float d21 = (Sx - 2.0f * a1) + sc[k + 1];
      float d22 = (Sx - 2.0f * a2) + sc[k + 2];
      float d23 = (Sx - 2.0f * a3) + sc[k + 3];
      if (d20 < m1) { m1 = d20; i1 = k + 0; }   // in-order: lowest index wins
      if (d21 < m1) { m1 = d21; i1 = k + 1; }
      if (d22 < m1) { m1 = d22; i1 = k + 2; }
      if (d23 < m1) { m1 = d23; i1 = k + 3; }
    }

    // Merge the 4 slices per pixel, in slice order (strict '<').
    __shared__ float sh_m[4][64];
    __shared__ int sh_i[4][64];
    __shared__ int sh_w[64];
    sh_m[wave][p] = m1;
    sh_i[wave][p] = i1;
    __syncthreads();
    if (wave == 0) {
      float mm = sh_m[0][p];
      int ii = sh_i[0][p];
#pragma unroll
      for (int s = 1; s < 4; ++s) {
        float ms = sh_m[s][p];
        int is = sh_i[s][p];
        if (ms < mm) { mm = ms; ii = is; }
      }
      sh_w[p] = ii;
      idx_out[g] = (float)ii;                   // 256 B coalesced store
    }
    __syncthreads();
    const int widx = sh_w[p];

    // Epilogue: wave handles 16 of the 64 dims for its 64 pixels.
    const float4* q4 = (const float4*)(cb + (size_t)widx * ND) + wave * 4;
    float* op = out + (size_t)b * (ND * NHW) + hw;
    const int dbase = wave * 16;
    float lossp = 0.f;
#pragma unroll
    for (int j = 0; j < 4; ++j) {
      float4 q = q4[j];
      int d = dbase + j * 4;
      float e;
      e = xr[d + 0] - q.x; lossp = __builtin_fmaf(e, e, lossp); op[(size_t)(d + 0) * NHW] = q.x;
      e = xr[d + 1] - q.y; lossp = __builtin_fmaf(e, e, lossp); op[(size_t)(d + 1) * NHW] = q.y;
      e = xr[d + 2] - q.z; lossp = __builtin_fmaf(e, e, lossp); op[(size_t)(d + 2) * NHW] = q.z;
      e = xr[d + 3] - q.w; lossp = __builtin_fmaf(e, e, lossp); op[(size_t)(d + 3) * NHW] = q.w;
    }

    // Loss reduction: wave shuffle + LDS + one atomic pair per block.
#pragma unroll
    for (int off = 32; off; off >>= 1) lossp += __shfl_down(lossp, off);
    __shared__ float red[4];
    if (p == 0) red[wave] = lossp;
    __syncthreads();
    if (tid == 0) {
      float t = (red[0] + red[1] + red[2] + red[3]) * (1.f / 8388608.f);
      atomicAdd(losses + 0, t);   // dictionary_loss
      atomicAdd(losses + 1, t);   // commitment_loss (identical forward value)
    }
  }
}

extern "C" void kernel_launch(void* const* d_in, const int* in_sizes, int n_in,
                              void* d_out, int out_size, void* d_ws, size_t ws_size,
                              hipStream_t stream) {
  const float* x  = (const float*)d_in[0];   // [32,64,64,64] fp32
  const float* cb = (const float*)d_in[1];   // [512,64] fp32
  float* out     = (float*)d_out;            // quantized [B,D,H,W]
  float* idx_out = out + OUT_ELEMS;          // indices (as fp32) [B,H,W]
  float* losses  = idx_out + NPIX;           // 2 scalars
  float* sc      = (float*)d_ws;             // 512 floats scratch

  vq_prep<<<2, 256, 0, stream>>>(cb, sc, losses);
  vq_main<<<NPIX / 64, 256, 0, stream>>>(x, cb, sc, out, idx_out, losses);
}

// Round 5
// 231.259 us; speedup vs baseline: 2.5008x; 1.1264x over previous
//
#include <hip/hip_runtime.h>

#define NK 512
#define ND 64
#define NHW 4096
#define NPIX 131072            // 32*64*64
#define OUT_ELEMS 8388608      // 32*64*64*64
#define XS 68                  // LDS row stride in floats (16B-aligned, uniform banks)

// ---------------------------------------------------------------------------
// Prep: sc[k] = numpy-pairwise-8 fp32 sum of fl(c_d^2); zero the two loss
// slots (harness re-poisons d_out/d_ws to 0xAA before every timed replay).
// ---------------------------------------------------------------------------
__global__ __launch_bounds__(256) void vq_prep(const float* __restrict__ cb,
                                               float* __restrict__ sc,
                                               float* __restrict__ losses) {
#pragma clang fp contract(off)
  {
    int k = blockIdx.x * 256 + threadIdx.x;   // grid 2*256 = 512
    const float* c = cb + (size_t)k * ND;
    float q[ND];
#pragma unroll
    for (int d = 0; d < ND; ++d) q[d] = c[d] * c[d];
    float r[8];
#pragma unroll
    for (int j = 0; j < 8; ++j) r[j] = q[j];
#pragma unroll
    for (int i = 8; i < ND; i += 8)
#pragma unroll
      for (int j = 0; j < 8; ++j) r[j] += q[i + j];
    float res = ((r[0] + r[1]) + (r[2] + r[3])) + ((r[4] + r[5]) + (r[6] + r[7]));
    sc[k] = res;
    if (k < 2) losses[k] = 0.f;
  }
}

// ---------------------------------------------------------------------------
// Main: 64 pixels/block, 4 waves = 4 K-slices of 128 codes. x tile lives in
// LDS (not per-thread registers — rounds 2-4 proved the allocator will not
// keep a 64-float array resident: it spilled 134 MB of scratch writes in R4).
// K-loop: 8 parallel sequential-FMA chains per group; each ds_read_b128
// feeds 32 FMAs, so LDS traffic (2.1 GB) sits well under the 55 us VALU
// floor. Codebook goes through the scalar path (readfirstlane slice id).
// Numerics bit-identical to the passing R2 kernel:
//   d2[k] = fl(fl(Sx - fl(2*M[k])) + Sc[k]), M[k] sequential fp32 FMA chain
//   d=0..63, Sx numpy pairwise-8; slice merge ascending, strict '<'
//   => lowest index wins ties = np.argmin over full K.
// ---------------------------------------------------------------------------
__global__ __launch_bounds__(256) void vq_main(const float* __restrict__ x,
                                               const float* __restrict__ cb,
                                               const float* __restrict__ sc,
                                               float* __restrict__ out,
                                               float* __restrict__ idx_out,
                                               float* __restrict__ losses) {
#pragma clang fp contract(off)
  {
    __shared__ float lx[64 * XS];          // 17.4 KB x tile [pixel][d]
    __shared__ float sh_m[4][64];
    __shared__ int sh_i[4][64];
    __shared__ int sh_w[64];
    __shared__ float red[4];

    const int tid = threadIdx.x;
    const int p = tid & 63;                                    // pixel lane
    const int wv = __builtin_amdgcn_readfirstlane(tid >> 6);   // slice, SGPR
    const int b = blockIdx.x >> 6;                             // image
    const int hw0 = (blockIdx.x & 63) << 6;                    // tile base
    const float* xbase = x + (size_t)b * (ND * NHW) + hw0;

    // ---- Stage x tile: thread (p, wv) loads quads dq = wv, wv+4, wv+8, wv+12.
    // Global side: per-d loads are 64-lane contiguous (coalesced).
#pragma unroll
    for (int i = 0; i < 4; ++i) {
      const int dq = wv + i * 4;
      const int d = dq * 4;
      float4 q;
      q.x = xbase[(size_t)(d + 0) * NHW + p];
      q.y = xbase[(size_t)(d + 1) * NHW + p];
      q.z = xbase[(size_t)(d + 2) * NHW + p];
      q.w = xbase[(size_t)(d + 3) * NHW + p];
      *(float4*)&lx[p * XS + d] = q;
    }
    __syncthreads();

    // ---- Sx = np.sum(x*x): rounded squares, pairwise-8 (bitwise = R2).
    float r[8];
    {
      float4 q0 = *(const float4*)&lx[p * XS + 0];
      float4 q1 = *(const float4*)&lx[p * XS + 4];
      r[0] = q0.x * q0.x; r[1] = q0.y * q0.y; r[2] = q0.z * q0.z; r[3] = q0.w * q0.w;
      r[4] = q1.x * q1.x; r[5] = q1.y * q1.y; r[6] = q1.z * q1.z; r[7] = q1.w * q1.w;
#pragma unroll
      for (int i = 2; i < 16; i += 2) {
        float4 a = *(const float4*)&lx[p * XS + i * 4];
        float4 c = *(const float4*)&lx[p * XS + i * 4 + 4];
        r[0] += a.x * a.x; r[1] += a.y * a.y; r[2] += a.z * a.z; r[3] += a.w * a.w;
        r[4] += c.x * c.x; r[5] += c.y * c.y; r[6] += c.z * c.z; r[7] += c.w * c.w;
      }
    }
    const float Sx = ((r[0] + r[1]) + (r[2] + r[3])) + ((r[4] + r[5]) + (r[6] + r[7]));

    // ---- K-slice [wv*128, wv*128+128), 8 chains per group.
    const int k0 = wv << 7;
    float m1 = 3.0e38f;
    int i1 = k0;

    for (int kk = 0; kk < 128; kk += 8) {
      const int k = k0 + kk;
      const float* cbase = cb + (size_t)k * ND;   // wave-uniform -> s_load
      float a0 = 0.f, a1 = 0.f, a2 = 0.f, a3 = 0.f;
      float a4 = 0.f, a5 = 0.f, a6 = 0.f, a7 = 0.f;
#pragma unroll
      for (int dq = 0; dq < 16; ++dq) {
        const float4 xq = *(const float4*)&lx[p * XS + dq * 4];
        const int d = dq * 4;
#define VQ_STEP(J, AJ)                                              \
        AJ = __builtin_fmaf(cbase[J * ND + d + 0], xq.x, AJ);       \
        AJ = __builtin_fmaf(cbase[J * ND + d + 1], xq.y, AJ);       \
        AJ = __builtin_fmaf(cbase[J * ND + d + 2], xq.z, AJ);       \
        AJ = __builtin_fmaf(cbase[J * ND + d + 3], xq.w, AJ);
        VQ_STEP(0, a0) VQ_STEP(1, a1) VQ_STEP(2, a2) VQ_STEP(3, a3)
        VQ_STEP(4, a4) VQ_STEP(5, a5) VQ_STEP(6, a6) VQ_STEP(7, a7)
#undef VQ_STEP
      }
      float d2v[8];
      d2v[0] = (Sx - 2.0f * a0) + sc[k + 0];
      d2v[1] = (Sx - 2.0f * a1) + sc[k + 1];
      d2v[2] = (Sx - 2.0f * a2) + sc[k + 2];
      d2v[3] = (Sx - 2.0f * a3) + sc[k + 3];
      d2v[4] = (Sx - 2.0f * a4) + sc[k + 4];
      d2v[5] = (Sx - 2.0f * a5) + sc[k + 5];
      d2v[6] = (Sx - 2.0f * a6) + sc[k + 6];
      d2v[7] = (Sx - 2.0f * a7) + sc[k + 7];
#pragma unroll
      for (int j = 0; j < 8; ++j)
        if (d2v[j] < m1) { m1 = d2v[j]; i1 = k + j; }   // in-order ties
    }

    // ---- Merge 4 slices per pixel, ascending slice order, strict '<'.
    sh_m[wv][p] = m1;
    sh_i[wv][p] = i1;
    __syncthreads();
    if (wv == 0) {
      float mm = sh_m[0][p];
      int ii = sh_i[0][p];
#pragma unroll
      for (int s = 1; s < 4; ++s) {
        float ms = sh_m[s][p];
        int is = sh_i[s][p];
        if (ms < mm) { mm = ms; ii = is; }
      }
      sh_w[p] = ii;
      idx_out[blockIdx.x * 64 + p] = (float)ii;   // coalesced
    }
    __syncthreads();
    const int widx = sh_w[p];

    // ---- Epilogue: wave wv writes dims [wv*16, wv*16+16) for its 64 pixels.
    const float4* q4 = (const float4*)(cb + (size_t)widx * ND) + wv * 4;
    float* op = out + (size_t)b * (ND * NHW) + hw0 + p;
    float lossp = 0.f;
#pragma unroll
    for (int j = 0; j < 4; ++j) {
      const float4 q = q4[j];
      const int d = wv * 16 + j * 4;
      const float4 xq = *(const float4*)&lx[p * XS + d];
      float e;
      e = xq.x - q.x; lossp = __builtin_fmaf(e, e, lossp); op[(size_t)(d + 0) * NHW] = q.x;
      e = xq.y - q.y; lossp = __builtin_fmaf(e, e, lossp); op[(size_t)(d + 1) * NHW] = q.y;
      e = xq.z - q.z; lossp = __builtin_fmaf(e, e, lossp); op[(size_t)(d + 2) * NHW] = q.z;
      e = xq.w - q.w; lossp = __builtin_fmaf(e, e, lossp); op[(size_t)(d + 3) * NHW] = q.w;
    }

    // ---- Loss reduction: wave shuffle + LDS + one atomic pair per block.
#pragma unroll
    for (int off = 32; off; off >>= 1) lossp += __shfl_down(lossp, off);
    if (p == 0) red[wv] = lossp;
    __syncthreads();
    if (tid == 0) {
      float t = (red[0] + red[1] + red[2] + red[3]) * (1.f / 8388608.f);
      atomicAdd(losses + 0, t);   // dictionary_loss
      atomicAdd(losses + 1, t);   // commitment_loss (identical forward value)
    }
  }
}

extern "C" void kernel_launch(void* const* d_in, const int* in_sizes, int n_in,
                              void* d_out, int out_size, void* d_ws, size_t ws_size,
                              hipStream_t stream) {
  const float* x  = (const float*)d_in[0];   // [32,64,64,64] fp32
  const float* cb = (const float*)d_in[1];   // [512,64] fp32
  float* out     = (float*)d_out;            // quantized [B,D,H,W]
  float* idx_out = out + OUT_ELEMS;          // indices (as fp32) [B,H,W]
  float* losses  = idx_out + NPIX;           // 2 scalars
  float* sc      = (float*)d_ws;             // 512 floats scratch

  vq_prep<<<2, 256, 0, stream>>>(cb, sc, losses);
  vq_main<<<NPIX / 64, 256, 0, stream>>>(x, cb, sc, out, idx_out, losses);
}